// Round 2
// baseline (230.830 us; speedup 1.0000x reference)
//
#include <hip/hip_runtime.h>
#include <hip/hip_cooperative_groups.h>

namespace cg = cooperative_groups;

typedef short s16x8 __attribute__((ext_vector_type(8)));
typedef float f32x4 __attribute__((ext_vector_type(4)));

#define NB      1024
#define NCLASS  50
#define NCENTER 8
#define HID     512
#define KPAD    64

// workspace byte offsets (16B aligned)
#define OFF_WT     0u          // 512*512*2 = 524288
#define OFF_MUBF   524288u     // 8*64*512*2 = 524288
#define OFF_MUNORM 1048576u    // 8*64*4 = 2048
#define OFF_MULBF  1050624u    // 8192*512*2 = 8388608
// total ~9.4 MB

// output layout (element offsets in d_out, fp32)
#define OUT_KA 4194304   // after mul [1024*8*512]
#define OUT_D  4603904   // after k_assign [1024*50*8]

// LDS row strides (shorts). 40 shorts = 80 B = 20 banks: 16-lane fragment
// reads at this stride cover all 32 banks with uniform 2-way aliasing (free),
// vs 8-way conflict at the old 64 B stride.
#define ASTR 40
#define SMEM_BYTES 16640   // max(prep 64*65*4, gemm (64+128)*40*2, score 16*16*9*4)

__device__ __forceinline__ short f2bf(float f) {
    unsigned int u = __float_as_uint(f);
    unsigned int r = (u + 0x7FFFu + ((u >> 16) & 1u)) >> 16;  // RNE
    return (short)(unsigned short)r;
}
__device__ __forceinline__ float bf2f(short h) {
    return __uint_as_float(((unsigned int)(unsigned short)h) << 16);
}

// ---------------------------------------------------------------------------
// Phase 0: blocks [0,64): W^T -> bf16 (LDS transpose); [64,192): class_mu ->
// padded bf16 + fp32 norms. Other blocks idle.
// ---------------------------------------------------------------------------
__device__ __forceinline__ void prep_body(int blk, int tid, char* smem,
    const float* __restrict__ class_mu, const float* __restrict__ W,
    short* __restrict__ WT, short* __restrict__ Mubf, float* __restrict__ Munorm)
{
    if (blk < 64) {
        float (*lds)[65] = (float (*)[65])smem;
        int th = blk & 7, td = blk >> 3;          // h-tile, d-tile
        int col = tid & 63, rb = tid >> 6;
        #pragma unroll
        for (int it = 0; it < 16; ++it) {
            int row = it * 4 + rb;
            lds[row][col] = W[(th * 64 + row) * HID + td * 64 + col];
        }
        __syncthreads();
        #pragma unroll
        for (int it = 0; it < 16; ++it) {
            int row = it * 4 + rb;
            WT[(td * 64 + row) * HID + th * 64 + col] = f2bf(lds[col][row]);
        }
    } else if (blk < 192) {
        // one wave per (c, kk): Mubf[c][kk][h] (kk>=50 zero-padded), Munorm
        int w = (blk - 64) * 4 + (tid >> 6);   // 0..511
        int lane = tid & 63;
        int c = w >> 6, kk = w & 63;
        int h = lane * 8;
        float v[8];
        if (kk < NCLASS) {
            const float4* p = (const float4*)(class_mu + (kk * NCENTER + c) * HID + h);
            float4 a = p[0], bq = p[1];
            v[0] = a.x;  v[1] = a.y;  v[2] = a.z;  v[3] = a.w;
            v[4] = bq.x; v[5] = bq.y; v[6] = bq.z; v[7] = bq.w;
        } else {
            #pragma unroll
            for (int j = 0; j < 8; ++j) v[j] = 0.f;
        }
        s16x8 o; float sq = 0.f;
        #pragma unroll
        for (int j = 0; j < 8; ++j) { o[j] = f2bf(v[j]); sq += v[j] * v[j]; }
        *(s16x8*)(Mubf + (c * KPAD + kk) * HID + h) = o;
        sq += __shfl_xor(sq, 1);  sq += __shfl_xor(sq, 2);  sq += __shfl_xor(sq, 4);
        sq += __shfl_xor(sq, 8);  sq += __shfl_xor(sq, 16); sq += __shfl_xor(sq, 32);
        if (lane == 0) Munorm[c * KPAD + kk] = sq;
    }
}

// ---------------------------------------------------------------------------
// Phase 1: mul = A @ W, A built on the fly: A[(b*8+c),k] = bf16(x[b,k]*mask[c,k]).
// 512 blocks (XCD-chunk swizzled), BM=64 x BN=128, 4 waves 2x2, each 32x64.
// LDS rows padded to 40 shorts -> conflict-free ds_read_b128/ds_write_b128.
// Writes fp32 mul to out and bf16 copy for the score phase.
// ---------------------------------------------------------------------------
__device__ __forceinline__ void gemm_body(int blk, int tid, char* smem,
    const float* __restrict__ x, const float* __restrict__ mask,
    const short* __restrict__ WT, float* __restrict__ mul_out,
    short* __restrict__ mulbf)
{
    short* As = (short*)smem;             // [64][ASTR]
    short* Bs = (short*)smem + 64 * ASTR; // [128][ASTR]
    const int swz = (blk & 7) * 64 + (blk >> 3);   // XCD-contiguous chunks
    const int bm = (swz >> 2) * 64;
    const int bn = (swz & 3) * 128;
    const int wave = tid >> 6, lane = tid & 63;
    const int wm = (wave & 1) * 32, wn = (wave >> 1) * 64;
    const int q = lane >> 4, l16 = lane & 15;

    f32x4 acc[2][4] = {};

    // staging: thread -> A row r0 (8 elems at c0), B rows r0 and r0+64
    const int r0 = tid >> 2, c0 = (tid & 3) * 8;
    const int xr = (bm >> 3) + (r0 >> 3);   // x row feeding A row r0 (c = r0&7)
    const float* xp = x + xr * HID + c0;
    const float* mp = mask + (r0 & 7) * HID + c0;
    const short* wp = WT + (bn + r0) * HID + c0;

    float4 xa, xb, ma, mb; s16x8 w0, w1;
#define GLOAD(IT) do { const int kq = (IT) * 32; \
        xa = *(const float4*)(xp + kq); xb = *(const float4*)(xp + kq + 4); \
        ma = *(const float4*)(mp + kq); mb = *(const float4*)(mp + kq + 4); \
        w0 = *(const s16x8*)(wp + kq);  w1 = *(const s16x8*)(wp + 64 * HID + kq); } while (0)

    GLOAD(0);
    #pragma unroll
    for (int it = 0; it < 16; ++it) {
        s16x8 oa;
        oa[0] = f2bf(xa.x * ma.x); oa[1] = f2bf(xa.y * ma.y);
        oa[2] = f2bf(xa.z * ma.z); oa[3] = f2bf(xa.w * ma.w);
        oa[4] = f2bf(xb.x * mb.x); oa[5] = f2bf(xb.y * mb.y);
        oa[6] = f2bf(xb.z * mb.z); oa[7] = f2bf(xb.w * mb.w);
        s16x8 cw0 = w0, cw1 = w1;
        if (it < 15) GLOAD(it + 1);        // prefetch next tile into regs

        __syncthreads();                   // prev iter's LDS reads done
        *(s16x8*)(As + r0 * ASTR + c0)        = oa;
        *(s16x8*)(Bs + r0 * ASTR + c0)        = cw0;
        *(s16x8*)(Bs + (r0 + 64) * ASTR + c0) = cw1;
        __syncthreads();

        s16x8 af[2], bfr[4];
        #pragma unroll
        for (int mt = 0; mt < 2; ++mt)
            af[mt] = *(const s16x8*)(As + (wm + mt * 16 + l16) * ASTR + q * 8);
        #pragma unroll
        for (int nt = 0; nt < 4; ++nt)
            bfr[nt] = *(const s16x8*)(Bs + (wn + nt * 16 + l16) * ASTR + q * 8);
        #pragma unroll
        for (int mt = 0; mt < 2; ++mt)
            #pragma unroll
            for (int nt = 0; nt < 4; ++nt)
                acc[mt][nt] = __builtin_amdgcn_mfma_f32_16x16x32_bf16(af[mt], bfr[nt], acc[mt][nt], 0, 0, 0);
    }
#undef GLOAD

    // epilogue: C/D layout col=lane&15, row=(lane>>4)*4+reg
    #pragma unroll
    for (int mt = 0; mt < 2; ++mt)
        #pragma unroll
        for (int nt = 0; nt < 4; ++nt)
            #pragma unroll
            for (int reg = 0; reg < 4; ++reg) {
                int gr = bm + wm + mt * 16 + q * 4 + reg;
                int gc = bn + wn + nt * 16 + l16;
                float v = acc[mt][nt][reg];
                mul_out[gr * HID + gc] = v;
                mulbf[gr * HID + gc] = f2bf(v);
            }
}

// ---------------------------------------------------------------------------
// Phase 2: fused score + normalize. Blocks [0,256): (bt 0..63, kt 0..3),
// 4 waves; wave w handles centers {2w, 2w+1} over 16 b-rows x 16 classes with
// two interleaved MFMA chains (hides MFMA dep latency). Scores -> LDS
// [16][16][9], then in-block normalize over centers and write ka/distances.
// ---------------------------------------------------------------------------
__device__ __forceinline__ void score_body(int blk, int tid, char* smem,
    const short* __restrict__ mulbf, const short* __restrict__ Mubf,
    const float* __restrict__ Munorm, float* __restrict__ out)
{
    if (blk >= 256) return;
    float (*sc)[16][9] = (float (*)[16][9])smem;   // [b][k][c]
    const int bt = blk >> 2, kt = blk & 3;
    const int b0 = bt * 16, kbase = kt * 16;
    const int wave = tid >> 6, lane = tid & 63;
    const int q = lane >> 4, l16 = lane & 15;
    const int ca = wave * 2, cb = ca + 1;

    f32x4 acc0 = {}, acc1 = {};
    float nrm0 = 0.f, nrm1 = 0.f;

    const short* arow = mulbf + ((b0 + l16) * NCENTER + ca) * HID + q * 8;
    const short* brow = Mubf + (ca * KPAD + kbase + l16) * HID + q * 8;

    #pragma unroll 4
    for (int it = 0; it < 16; ++it) {
        const int k0 = it * 32;
        s16x8 a0 = *(const s16x8*)(arow + k0);
        s16x8 a1 = *(const s16x8*)(arow + HID + k0);          // center cb
        s16x8 bv0 = *(const s16x8*)(brow + k0);
        s16x8 bv1 = *(const s16x8*)(brow + KPAD * HID + k0);  // center cb
        #pragma unroll
        for (int j = 0; j < 8; ++j) {
            float f0 = bf2f(a0[j]); nrm0 += f0 * f0;
            float f1 = bf2f(a1[j]); nrm1 += f1 * f1;
        }
        acc0 = __builtin_amdgcn_mfma_f32_16x16x32_bf16(a0, bv0, acc0, 0, 0, 0);
        acc1 = __builtin_amdgcn_mfma_f32_16x16x32_bf16(a1, bv1, acc1, 0, 0, 0);
    }

    // row norms: lane (q,l16) covered k-chunk q of row l16; xor over q
    nrm0 += __shfl_xor(nrm0, 16); nrm0 += __shfl_xor(nrm0, 32);
    nrm1 += __shfl_xor(nrm1, 16); nrm1 += __shfl_xor(nrm1, 32);

    float mn0 = Munorm[ca * KPAD + kbase + l16];
    float mn1 = Munorm[cb * KPAD + kbase + l16];
    #pragma unroll
    for (int reg = 0; reg < 4; ++reg) {
        float rn0 = __shfl(nrm0, q * 4 + reg);       // norm of row b0+q*4+reg
        float rn1 = __shfl(nrm1, q * 4 + reg);
        sc[q * 4 + reg][l16][ca] = 1.f / (1.f + rn0 + mn0 - 2.f * acc0[reg]);
        sc[q * 4 + reg][l16][cb] = 1.f / (1.f + rn1 + mn1 - 2.f * acc1[reg]);
    }
    __syncthreads();

    {   // 256 threads: one (b,k) each
        int b = tid >> 4, k = tid & 15;
        int kcls = kbase + k;
        if (kcls < NCLASS) {
            float s0 = sc[b][k][0], s1 = sc[b][k][1], s2 = sc[b][k][2], s3 = sc[b][k][3];
            float s4 = sc[b][k][4], s5 = sc[b][k][5], s6 = sc[b][k][6], s7 = sc[b][k][7];
            float S = ((s0 + s1) + (s2 + s3)) + ((s4 + s5) + (s6 + s7));
            float invd = 1.f / (S + 1e-8f);   // distances = score/(S+eps)
            float invk = 1.f / S;             // k_assign  = score/S
            float* kap = out + OUT_KA + ((b0 + b) * NCLASS + kcls) * NCENTER;
            float* dp  = out + OUT_D  + ((b0 + b) * NCLASS + kcls) * NCENTER;
            float4 ka0 = {s0 * invk, s1 * invk, s2 * invk, s3 * invk};
            float4 ka1 = {s4 * invk, s5 * invk, s6 * invk, s7 * invk};
            float4 dd0 = {s0 * invd, s1 * invd, s2 * invd, s3 * invd};
            float4 dd1 = {s4 * invd, s5 * invd, s6 * invd, s7 * invd};
            ((float4*)kap)[0] = ka0; ((float4*)kap)[1] = ka1;
            ((float4*)dp)[0]  = dd0; ((float4*)dp)[1]  = dd1;
        }
    }
}

// ---------------------------------------------------------------------------
// Fused cooperative kernel: prep -> grid.sync -> gemm -> grid.sync -> score.
// 512 blocks x 256 thr; __launch_bounds__(256,2) caps VGPR<=256 so 2 blocks/CU
// are guaranteed co-resident (LDS 16.6 KB -> 9/CU; waves 4/block -> 8/CU).
// ---------------------------------------------------------------------------
__global__ void __launch_bounds__(256, 2) fused_kernel(
    const float* __restrict__ x, const float* __restrict__ class_mu,
    const float* __restrict__ mask, const float* __restrict__ W,
    short* __restrict__ WT, short* __restrict__ Mubf, float* __restrict__ Munorm,
    short* __restrict__ mulbf, float* __restrict__ out)
{
    __shared__ __align__(16) char smem[SMEM_BYTES];
    cg::grid_group grid = cg::this_grid();
    prep_body(blockIdx.x, threadIdx.x, smem, class_mu, W, WT, Mubf, Munorm);
    grid.sync();
    gemm_body(blockIdx.x, threadIdx.x, smem, x, mask, WT, out, mulbf);
    grid.sync();
    score_body(blockIdx.x, threadIdx.x, smem, mulbf, Mubf, Munorm, out);
}

// --------------------- fallback (plain launches) ---------------------------
__global__ void __launch_bounds__(256) prep_sep(
    const float* __restrict__ class_mu, const float* __restrict__ W,
    short* __restrict__ WT, short* __restrict__ Mubf, float* __restrict__ Munorm)
{
    __shared__ __align__(16) char smem[SMEM_BYTES];
    prep_body(blockIdx.x, threadIdx.x, smem, class_mu, W, WT, Mubf, Munorm);
}
__global__ void __launch_bounds__(256) gemm_sep(
    const float* __restrict__ x, const float* __restrict__ mask,
    const short* __restrict__ WT, float* __restrict__ mul_out, short* __restrict__ mulbf)
{
    __shared__ __align__(16) char smem[SMEM_BYTES];
    gemm_body(blockIdx.x, threadIdx.x, smem, x, mask, WT, mul_out, mulbf);
}
__global__ void __launch_bounds__(256) score_sep(
    const short* __restrict__ mulbf, const short* __restrict__ Mubf,
    const float* __restrict__ Munorm, float* __restrict__ out)
{
    __shared__ __align__(16) char smem[SMEM_BYTES];
    score_body(blockIdx.x, threadIdx.x, smem, mulbf, Mubf, Munorm, out);
}

extern "C" void kernel_launch(void* const* d_in, const int* in_sizes, int n_in,
                              void* d_out, int out_size, void* d_ws, size_t ws_size,
                              hipStream_t stream) {
    const float* x        = (const float*)d_in[0];
    const float* class_mu = (const float*)d_in[1];
    const float* mask     = (const float*)d_in[2];
    const float* W        = (const float*)d_in[3];
    float* out = (float*)d_out;
    char* ws = (char*)d_ws;

    short* WT     = (short*)(ws + OFF_WT);
    short* Mubf   = (short*)(ws + OFF_MUBF);
    float* Munorm = (float*)(ws + OFF_MUNORM);
    short* mulbf  = (short*)(ws + OFF_MULBF);

    void* args[] = { (void*)&x, (void*)&class_mu, (void*)&mask, (void*)&W,
                     (void*)&WT, (void*)&Mubf, (void*)&Munorm, (void*)&mulbf,
                     (void*)&out };
    hipError_t err = hipLaunchCooperativeKernel((const void*)fused_kernel,
                                                dim3(512), dim3(256), args, 0, stream);
    if (err != hipSuccess) {
        (void)hipGetLastError();  // clear sticky error, fall back to 3 launches
        prep_sep<<<192, 256, 0, stream>>>(class_mu, W, WT, Mubf, Munorm);
        gemm_sep<<<512, 256, 0, stream>>>(x, mask, WT, out, mulbf);
        score_sep<<<256, 256, 0, stream>>>(mulbf, Mubf, Munorm, out);
    }
}

// Round 3
// 93.449 us; speedup vs baseline: 2.4701x; 2.4701x over previous
//
#include <hip/hip_runtime.h>

typedef short s16x8 __attribute__((ext_vector_type(8)));
typedef float f32x4 __attribute__((ext_vector_type(4)));

#define NB      1024
#define NCLASS  50
#define NCENTER 8
#define HID     512
#define KPAD    64

// workspace byte offsets (16B aligned)
#define OFF_WT     0u          // 512*512*2 = 524288
#define OFF_MUBF   524288u     // 8*64*512*2 = 524288
#define OFF_MUNORM 1048576u    // 8*64*4 = 2048
#define OFF_MULBF  1050624u    // 8192*512*2 = 8388608
// total ~9.4 MB

// output layout (element offsets in d_out, fp32)
#define OUT_KA 4194304   // after mul [1024*8*512]
#define OUT_D  4603904   // after k_assign [1024*50*8]

// LDS row stride (shorts). 40 shorts = 80 B: within each 16-lane group a
// b128 read at this stride starts at 8 distinct bank-quads (2 lanes each,
// 2-way = free) vs 8-way at 64 B stride.
#define ASTR 40

__device__ __forceinline__ short f2bf(float f) {
    unsigned int u = __float_as_uint(f);
    unsigned int r = (u + 0x7FFFu + ((u >> 16) & 1u)) >> 16;  // RNE
    return (short)(unsigned short)r;
}
__device__ __forceinline__ float bf2f(short h) {
    return __uint_as_float(((unsigned int)(unsigned short)h) << 16);
}

// ---------------------------------------------------------------------------
// Kernel 1: prep. blocks [0,64): W^T -> bf16 (LDS transpose); [64,192):
// class_mu -> padded bf16 + fp32 norms. 192 blocks < 256 CUs: all parallel.
// ---------------------------------------------------------------------------
__global__ void __launch_bounds__(256) prep_kernel(
    const float* __restrict__ class_mu, const float* __restrict__ W,
    short* __restrict__ WT, short* __restrict__ Mubf, float* __restrict__ Munorm)
{
    __shared__ float lds[64][65];
    const int blk = blockIdx.x, tid = threadIdx.x;

    if (blk < 64) {
        int th = blk & 7, td = blk >> 3;          // h-tile, d-tile
        int col = tid & 63, rb = tid >> 6;
        #pragma unroll
        for (int it = 0; it < 16; ++it) {
            int row = it * 4 + rb;
            lds[row][col] = W[(th * 64 + row) * HID + td * 64 + col];
        }
        __syncthreads();
        #pragma unroll
        for (int it = 0; it < 16; ++it) {
            int row = it * 4 + rb;
            WT[(td * 64 + row) * HID + th * 64 + col] = f2bf(lds[col][row]);
        }
    } else {
        // one wave per (c, kk): Mubf[c][kk][h] (kk>=50 zero-padded), Munorm
        int w = (blk - 64) * 4 + (tid >> 6);   // 0..511
        int lane = tid & 63;
        int c = w >> 6, kk = w & 63;
        int h = lane * 8;
        float v[8];
        if (kk < NCLASS) {
            const float4* p = (const float4*)(class_mu + (kk * NCENTER + c) * HID + h);
            float4 a = p[0], bq = p[1];
            v[0] = a.x;  v[1] = a.y;  v[2] = a.z;  v[3] = a.w;
            v[4] = bq.x; v[5] = bq.y; v[6] = bq.z; v[7] = bq.w;
        } else {
            #pragma unroll
            for (int j = 0; j < 8; ++j) v[j] = 0.f;
        }
        s16x8 o; float sq = 0.f;
        #pragma unroll
        for (int j = 0; j < 8; ++j) { o[j] = f2bf(v[j]); sq += v[j] * v[j]; }
        *(s16x8*)(Mubf + (c * KPAD + kk) * HID + h) = o;
        sq += __shfl_xor(sq, 1);  sq += __shfl_xor(sq, 2);  sq += __shfl_xor(sq, 4);
        sq += __shfl_xor(sq, 8);  sq += __shfl_xor(sq, 16); sq += __shfl_xor(sq, 32);
        if (lane == 0) Munorm[c * KPAD + kk] = sq;
    }
}

// ---------------------------------------------------------------------------
// Kernel 2: mul = A @ W, A built on the fly: A[(b*8+c),k] = bf16(x[b,k]*mask[c,k]).
// 512 blocks (XCD-chunk swizzled: XCD x owns bm tiles [16x,16x+16)), BM=64 x
// BN=128, 4 waves 2x2. LDS rows padded to ASTR=40. Writes fp32 mul (output)
// and bf16 mulbf for the score kernel.
// ---------------------------------------------------------------------------
__global__ void __launch_bounds__(256, 2) gemm_mul(
    const float* __restrict__ x, const float* __restrict__ mask,
    const short* __restrict__ WT, float* __restrict__ mul_out,
    short* __restrict__ mulbf)
{
    __shared__ short As[64 * ASTR];
    __shared__ short Bs[128 * ASTR];
    const int tid = threadIdx.x;
    const int blk = blockIdx.x;
    const int swz = (blk & 7) * 64 + (blk >> 3);   // XCD-contiguous chunks
    const int bm = (swz >> 2) * 64;
    const int bn = (swz & 3) * 128;
    const int wave = tid >> 6, lane = tid & 63;
    const int wm = (wave & 1) * 32, wn = (wave >> 1) * 64;
    const int q = lane >> 4, l16 = lane & 15;

    f32x4 acc[2][4] = {};

    // staging: thread -> A row r0 (8 elems at c0), B rows r0 and r0+64
    const int r0 = tid >> 2, c0 = (tid & 3) * 8;
    const int xr = (bm >> 3) + (r0 >> 3);   // x row feeding A row r0 (c = r0&7)
    const float* xp = x + xr * HID + c0;
    const float* mp = mask + (r0 & 7) * HID + c0;
    const short* wp = WT + (bn + r0) * HID + c0;

    float4 xa, xb, ma, mb; s16x8 w0, w1;
#define GLOAD(IT) do { const int kq = (IT) * 32; \
        xa = *(const float4*)(xp + kq); xb = *(const float4*)(xp + kq + 4); \
        ma = *(const float4*)(mp + kq); mb = *(const float4*)(mp + kq + 4); \
        w0 = *(const s16x8*)(wp + kq);  w1 = *(const s16x8*)(wp + 64 * HID + kq); } while (0)

    GLOAD(0);
    #pragma unroll
    for (int it = 0; it < 16; ++it) {
        s16x8 oa;
        oa[0] = f2bf(xa.x * ma.x); oa[1] = f2bf(xa.y * ma.y);
        oa[2] = f2bf(xa.z * ma.z); oa[3] = f2bf(xa.w * ma.w);
        oa[4] = f2bf(xb.x * mb.x); oa[5] = f2bf(xb.y * mb.y);
        oa[6] = f2bf(xb.z * mb.z); oa[7] = f2bf(xb.w * mb.w);
        s16x8 cw0 = w0, cw1 = w1;
        if (it < 15) GLOAD(it + 1);        // prefetch next tile into regs

        __syncthreads();                   // prev iter's LDS reads done
        *(s16x8*)(As + r0 * ASTR + c0)        = oa;
        *(s16x8*)(Bs + r0 * ASTR + c0)        = cw0;
        *(s16x8*)(Bs + (r0 + 64) * ASTR + c0) = cw1;
        __syncthreads();

        s16x8 af[2], bfr[4];
        #pragma unroll
        for (int mt = 0; mt < 2; ++mt)
            af[mt] = *(const s16x8*)(As + (wm + mt * 16 + l16) * ASTR + q * 8);
        #pragma unroll
        for (int nt = 0; nt < 4; ++nt)
            bfr[nt] = *(const s16x8*)(Bs + (wn + nt * 16 + l16) * ASTR + q * 8);
        #pragma unroll
        for (int mt = 0; mt < 2; ++mt)
            #pragma unroll
            for (int nt = 0; nt < 4; ++nt)
                acc[mt][nt] = __builtin_amdgcn_mfma_f32_16x16x32_bf16(af[mt], bfr[nt], acc[mt][nt], 0, 0, 0);
    }
#undef GLOAD

    // epilogue: C/D layout col=lane&15, row=(lane>>4)*4+reg
    #pragma unroll
    for (int mt = 0; mt < 2; ++mt)
        #pragma unroll
        for (int nt = 0; nt < 4; ++nt)
            #pragma unroll
            for (int reg = 0; reg < 4; ++reg) {
                int gr = bm + wm + mt * 16 + q * 4 + reg;
                int gc = bn + wn + nt * 16 + l16;
                float v = acc[mt][nt][reg];
                mul_out[gr * HID + gc] = v;
                mulbf[gr * HID + gc] = f2bf(v);
            }
}

// ---------------------------------------------------------------------------
// Kernel 3: fused score + normalize. 256 blocks x 256 thr. Block id decode is
// XCD-aligned with the gemm producer: raw&7 = XCD x -> bt in [8x,8x+8), so
// the mulbf rows this block reads were written by gemm blocks on the same
// XCD (2 MB/XCD, L2-resident). 4 waves; wave w = centers {2w,2w+1}, 16 b-rows
// x 16 classes via dual MFMA chains; scores -> LDS [16][16][9]; in-block
// normalize over the 8 centers; write k_assign + distances.
// ---------------------------------------------------------------------------
__global__ void __launch_bounds__(256) score_norm_kernel(
    const short* __restrict__ mulbf, const short* __restrict__ Mubf,
    const float* __restrict__ Munorm, float* __restrict__ out)
{
    __shared__ float sc[16][16][9];   // [b][k][c], pad 9
    const int raw = blockIdx.x, tid = threadIdx.x;
    const int bt = (raw & 7) * 8 + (raw >> 5);   // XCD (raw&7) owns bt in [8x,8x+8)
    const int kt = (raw >> 3) & 3;
    const int b0 = bt * 16, kbase = kt * 16;
    const int wave = tid >> 6, lane = tid & 63;
    const int q = lane >> 4, l16 = lane & 15;
    const int ca = wave * 2, cb = ca + 1;

    f32x4 acc0 = {}, acc1 = {};
    float nrm0 = 0.f, nrm1 = 0.f;

    const short* arow = mulbf + ((b0 + l16) * NCENTER + ca) * HID + q * 8;
    const short* brow = Mubf + (ca * KPAD + kbase + l16) * HID + q * 8;

    #pragma unroll 4
    for (int it = 0; it < 16; ++it) {
        const int k0 = it * 32;
        s16x8 a0 = *(const s16x8*)(arow + k0);
        s16x8 a1 = *(const s16x8*)(arow + HID + k0);          // center cb (next row)
        s16x8 bv0 = *(const s16x8*)(brow + k0);
        s16x8 bv1 = *(const s16x8*)(brow + KPAD * HID + k0);  // center cb
        #pragma unroll
        for (int j = 0; j < 8; ++j) {
            float f0 = bf2f(a0[j]); nrm0 += f0 * f0;
            float f1 = bf2f(a1[j]); nrm1 += f1 * f1;
        }
        acc0 = __builtin_amdgcn_mfma_f32_16x16x32_bf16(a0, bv0, acc0, 0, 0, 0);
        acc1 = __builtin_amdgcn_mfma_f32_16x16x32_bf16(a1, bv1, acc1, 0, 0, 0);
    }

    // row norms: lane (q,l16) covered k-chunk q of A-row l16; xor over q
    nrm0 += __shfl_xor(nrm0, 16); nrm0 += __shfl_xor(nrm0, 32);
    nrm1 += __shfl_xor(nrm1, 16); nrm1 += __shfl_xor(nrm1, 32);

    float mn0 = Munorm[ca * KPAD + kbase + l16];
    float mn1 = Munorm[cb * KPAD + kbase + l16];
    #pragma unroll
    for (int reg = 0; reg < 4; ++reg) {
        float rn0 = __shfl(nrm0, q * 4 + reg);       // norm of A-row q*4+reg
        float rn1 = __shfl(nrm1, q * 4 + reg);
        sc[q * 4 + reg][l16][ca] = 1.f / (1.f + rn0 + mn0 - 2.f * acc0[reg]);
        sc[q * 4 + reg][l16][cb] = 1.f / (1.f + rn1 + mn1 - 2.f * acc1[reg]);
    }
    __syncthreads();

    {   // 256 threads: one (b,k) each
        int b = tid >> 4, k = tid & 15;
        int kcls = kbase + k;
        if (kcls < NCLASS) {
            float s0 = sc[b][k][0], s1 = sc[b][k][1], s2 = sc[b][k][2], s3 = sc[b][k][3];
            float s4 = sc[b][k][4], s5 = sc[b][k][5], s6 = sc[b][k][6], s7 = sc[b][k][7];
            float S = ((s0 + s1) + (s2 + s3)) + ((s4 + s5) + (s6 + s7));
            float invd = 1.f / (S + 1e-8f);   // distances = score/(S+eps)
            float invk = 1.f / S;             // k_assign  = score/S
            float* kap = out + OUT_KA + ((b0 + b) * NCLASS + kcls) * NCENTER;
            float* dp  = out + OUT_D  + ((b0 + b) * NCLASS + kcls) * NCENTER;
            float4 ka0 = {s0 * invk, s1 * invk, s2 * invk, s3 * invk};
            float4 ka1 = {s4 * invk, s5 * invk, s6 * invk, s7 * invk};
            float4 dd0 = {s0 * invd, s1 * invd, s2 * invd, s3 * invd};
            float4 dd1 = {s4 * invd, s5 * invd, s6 * invd, s7 * invd};
            ((float4*)kap)[0] = ka0; ((float4*)kap)[1] = ka1;
            ((float4*)dp)[0]  = dd0; ((float4*)dp)[1]  = dd1;
        }
    }
}

extern "C" void kernel_launch(void* const* d_in, const int* in_sizes, int n_in,
                              void* d_out, int out_size, void* d_ws, size_t ws_size,
                              hipStream_t stream) {
    const float* x        = (const float*)d_in[0];
    const float* class_mu = (const float*)d_in[1];
    const float* mask     = (const float*)d_in[2];
    const float* W        = (const float*)d_in[3];
    float* out = (float*)d_out;
    char* ws = (char*)d_ws;

    short* WT     = (short*)(ws + OFF_WT);
    short* Mubf   = (short*)(ws + OFF_MUBF);
    float* Munorm = (float*)(ws + OFF_MUNORM);
    short* mulbf  = (short*)(ws + OFF_MULBF);

    prep_kernel<<<192, 256, 0, stream>>>(class_mu, W, WT, Mubf, Munorm);
    gemm_mul<<<512, 256, 0, stream>>>(x, mask, WT, out, mulbf);
    score_norm_kernel<<<256, 256, 0, stream>>>(mulbf, Mubf, Munorm, out);
}